// Round 2
// baseline (1409.929 us; speedup 1.0000x reference)
//
#include <hip/hip_runtime.h>
#include <hip/hip_bf16.h>

#define N_NODES   50000
#define DIM       128
#define NUM_GRAPHS 64
#define NUM_CLASSES 3

// ---------------- init: deg=1 (self loop), pooled=0, counts=0 ----------------
__global__ void k_init(float* deg, float* pooled, float* counts) {
    int i = blockIdx.x * 256 + threadIdx.x;
    if (i < N_NODES) deg[i] = 1.0f;
    if (i < NUM_GRAPHS * DIM) pooled[i] = 0.0f;
    if (i < NUM_GRAPHS) counts[i] = 0.0f;
}

// ---------------- degree accumulation over edges ----------------
__global__ void k_deg(const int* __restrict__ dst, float* deg, int nedges) {
    int e = blockIdx.x * 256 + threadIdx.x;
    if (e < nedges) atomicAdd(&deg[dst[e]], 1.0f);
}

__global__ void k_rsqrt(float* deg) {
    int i = blockIdx.x * 256 + threadIdx.x;
    if (i < N_NODES) deg[i] = rsqrtf(deg[i]);   // deg >= 1 always (self loop)
}

// ---------------- matmul: T = act(in) @ W ; A = b + T * dinv^2 ----------------
// Block: 256 threads, 32 rows. W fp32 in LDS (64 KB), x tile fp32 (16 KB).
// Thread (cg = tid&31, rl = tid>>5) computes rows rl*4..rl*4+3, cols 4cg..4cg+3.
template<bool RELU_IN>
__global__ __launch_bounds__(256) void k_matmul(
    const float* __restrict__ xin, const float* __restrict__ W,
    const float* __restrict__ b, const float* __restrict__ dinv,
    float* __restrict__ T, float* A)
{
    __shared__ float Wl[DIM * DIM];   // 64 KB
    __shared__ float Xl[32 * DIM];    // 16 KB

    const int tid = threadIdx.x;
    const int rowbase = blockIdx.x * 32;

    // stage W (16384 fp32 = 4096 float4)
    #pragma unroll
    for (int i = 0; i < 16; ++i) {
        int idx4 = tid + i * 256;
        ((float4*)Wl)[idx4] = ((const float4*)W)[idx4];
    }
    // stage X tile (32 rows x 128) fp32, with optional ReLU
    #pragma unroll
    for (int i = 0; i < 4; ++i) {
        int idx4 = tid + i * 256;          // 1024 float4 groups
        int row  = idx4 >> 5;              // 32 groups per row
        int grow = rowbase + row;
        float4 f = make_float4(0.f, 0.f, 0.f, 0.f);
        if (grow < N_NODES) {
            f = ((const float4*)xin)[rowbase * 32 + idx4];
            if (RELU_IN) {
                f.x = fmaxf(f.x, 0.f); f.y = fmaxf(f.y, 0.f);
                f.z = fmaxf(f.z, 0.f); f.w = fmaxf(f.w, 0.f);
            }
        }
        ((float4*)Xl)[idx4] = f;
    }
    __syncthreads();

    const int cg = tid & 31;
    const int r0 = (tid >> 5) * 4;

    float acc[4][4];
    #pragma unroll
    for (int i = 0; i < 4; ++i)
        #pragma unroll
        for (int j = 0; j < 4; ++j) acc[i][j] = 0.f;

    for (int k = 0; k < DIM; ++k) {
        float4 w = ((float4*)Wl)[k * 32 + cg];
        #pragma unroll
        for (int i = 0; i < 4; ++i) {
            float xv = Xl[(r0 + i) * DIM + k];
            acc[i][0] += xv * w.x;
            acc[i][1] += xv * w.y;
            acc[i][2] += xv * w.z;
            acc[i][3] += xv * w.w;
        }
    }

    float4 bv = ((const float4*)b)[cg];

    #pragma unroll
    for (int i = 0; i < 4; ++i) {
        int n = rowbase + r0 + i;
        if (n < N_NODES) {
            float di = dinv[n];
            float sl = di * di;
            float4 t = make_float4(acc[i][0], acc[i][1], acc[i][2], acc[i][3]);
            ((float4*)(T + (long long)n * DIM))[cg] = t;
            float4 a = make_float4(bv.x + t.x * sl, bv.y + t.y * sl,
                                   bv.z + t.z * sl, bv.w + t.w * sl);
            ((float4*)(A + (long long)n * DIM))[cg] = a;
        }
    }
}

// ---------------- edge scatter: A[d,:] += T[s,:] * dinv[s]*dinv[d] ----------------
__global__ __launch_bounds__(256) void k_scatter(
    const int* __restrict__ src, const int* __restrict__ dst,
    const float* __restrict__ dinv, const float* __restrict__ T,
    float* A, int nedges)
{
    int t = blockIdx.x * 256 + threadIdx.x;
    int e = t >> 7;
    int j = t & 127;
    if (e < nedges) {
        int s = src[e], d = dst[e];
        float w = dinv[s] * dinv[d];
        atomicAdd(&A[(long long)d * DIM + j], T[(long long)s * DIM + j] * w);
    }
}

// ---------------- pooling: run-length accumulate over sorted batch ----------------
#define NPB 512
__global__ __launch_bounds__(128) void k_pool(
    const float* __restrict__ h, const int* __restrict__ batch,
    float* pooled, float* counts)
{
    int j = threadIdx.x;
    int n0 = blockIdx.x * NPB;
    if (n0 >= N_NODES) return;
    int nend = min(n0 + NPB, N_NODES);
    int cur = batch[n0];
    int runstart = n0;
    float acc = 0.f;
    for (int n = n0; n < nend; ++n) {
        int g = batch[n];
        if (g != cur) {
            atomicAdd(&pooled[cur * DIM + j], acc);
            if (j == 0) atomicAdd(&counts[cur], (float)(n - runstart));
            acc = 0.f; cur = g; runstart = n;
        }
        acc += h[(long long)n * DIM + j];
    }
    atomicAdd(&pooled[cur * DIM + j], acc);
    if (j == 0) atomicAdd(&counts[cur], (float)(nend - runstart));
}

// ---------------- classifier head ----------------
__global__ __launch_bounds__(128) void k_cls(
    const float* __restrict__ pooled, const float* __restrict__ counts,
    const float* __restrict__ C1, const float* __restrict__ bc1,
    const float* __restrict__ C2, const float* __restrict__ bc2,
    float* out)
{
    __shared__ float pm[DIM];
    __shared__ float gv[DIM];
    int g = blockIdx.x, j = threadIdx.x;
    float cnt = fmaxf(counts[g], 1.0f);
    pm[j] = pooled[g * DIM + j] / cnt;
    __syncthreads();
    float a = bc1[j];
    for (int k = 0; k < DIM; ++k) a += pm[k] * C1[k * DIM + j];
    gv[j] = fmaxf(a, 0.f);
    __syncthreads();
    if (j < NUM_CLASSES) {
        float o = bc2[j];
        for (int k = 0; k < DIM; ++k) o += gv[k] * C2[k * NUM_CLASSES + j];
        out[g * NUM_CLASSES + j] = o;
    }
}

extern "C" void kernel_launch(void* const* d_in, const int* in_sizes, int n_in,
                              void* d_out, int out_size, void* d_ws, size_t ws_size,
                              hipStream_t stream) {
    const float* x    = (const float*)d_in[0];
    const int*   ei   = (const int*)d_in[1];
    const int*   batch= (const int*)d_in[2];
    const float* W1   = (const float*)d_in[3];
    const float* b1   = (const float*)d_in[4];
    const float* W2   = (const float*)d_in[5];
    const float* b2   = (const float*)d_in[6];
    const float* W3   = (const float*)d_in[7];
    const float* b3   = (const float*)d_in[8];
    const float* C1   = (const float*)d_in[9];
    const float* bc1  = (const float*)d_in[10];
    const float* C2   = (const float*)d_in[11];
    const float* bc2  = (const float*)d_in[12];

    const int nedges = in_sizes[1] / 2;
    const int* src = ei;
    const int* dst = ei + nedges;

    // workspace layout (floats)
    float* deg    = (float*)d_ws;               // 50176 (dinv in place)
    float* T      = deg + 50176;                // 6.4M
    float* A      = T + (long long)N_NODES*DIM; // 6.4M
    float* pooled = A + (long long)N_NODES*DIM; // 8192
    float* counts = pooled + NUM_GRAPHS * DIM;  // 64

    const int nodeBlocks = (N_NODES + 255) / 256;           // 196
    const int mmBlocks   = (N_NODES + 31) / 32;             // 1563
    const int scBlocks   = (nedges * 128 + 255) / 256;      // 400000
    const int poolBlocks = (N_NODES + NPB - 1) / NPB;       // 98

    k_init<<<nodeBlocks, 256, 0, stream>>>(deg, pooled, counts);
    k_deg<<<(nedges + 255) / 256, 256, 0, stream>>>(dst, deg, nedges);
    k_rsqrt<<<nodeBlocks, 256, 0, stream>>>(deg);

    // layer 1: in = x, no ReLU on input
    k_matmul<false><<<mmBlocks, 256, 0, stream>>>(x, W1, b1, deg, T, A);
    k_scatter<<<scBlocks, 256, 0, stream>>>(src, dst, deg, T, A, nedges);
    // layer 2: in = A, ReLU; in-place agg into A (blocks touch only own rows)
    k_matmul<true><<<mmBlocks, 256, 0, stream>>>(A, W2, b2, deg, T, A);
    k_scatter<<<scBlocks, 256, 0, stream>>>(src, dst, deg, T, A, nedges);
    // layer 3: in = A, ReLU
    k_matmul<true><<<mmBlocks, 256, 0, stream>>>(A, W3, b3, deg, T, A);
    k_scatter<<<scBlocks, 256, 0, stream>>>(src, dst, deg, T, A, nedges);

    k_pool<<<poolBlocks, 128, 0, stream>>>(A, batch, pooled, counts);
    k_cls<<<NUM_GRAPHS, 128, 0, stream>>>(pooled, counts, C1, bc1, C2, bc2,
                                          (float*)d_out);
}

// Round 3
// 858.486 us; speedup vs baseline: 1.6423x; 1.6423x over previous
//
#include <hip/hip_runtime.h>
#include <hip/hip_bf16.h>

#define N_NODES    50000
#define DIM        128
#define NUM_GRAPHS 64
#define NUM_CLASSES 3
#define NPAD       50176   // 196*256, padded node count

// ---------------- init: degi=0, pooled=0, counts=0 ----------------
__global__ void k_init(int* degi, float* pooled, float* counts) {
    int i = blockIdx.x * 256 + threadIdx.x;
    if (i < NPAD) degi[i] = 0;
    if (i < NUM_GRAPHS * DIM) pooled[i] = 0.0f;
    if (i < NUM_GRAPHS) counts[i] = 0.0f;
}

// ---------------- in-degree histogram ----------------
__global__ void k_count(const int* __restrict__ dst, int* degi, int nedges) {
    int e = blockIdx.x * 256 + threadIdx.x;
    if (e < nedges) atomicAdd(&degi[dst[e]], 1);
}

// ---------------- 3-phase exclusive scan over NPAD entries ----------------
__global__ __launch_bounds__(256) void k_scan1(const int* __restrict__ degi,
                                               int* rowptr, int* bsum) {
    __shared__ int sh[256];
    int i = blockIdx.x * 256 + threadIdx.x;
    int v = degi[i];
    sh[threadIdx.x] = v;
    __syncthreads();
    for (int off = 1; off < 256; off <<= 1) {
        int t = (threadIdx.x >= off) ? sh[threadIdx.x - off] : 0;
        __syncthreads();
        sh[threadIdx.x] += t;
        __syncthreads();
    }
    rowptr[i] = sh[threadIdx.x] - v;          // block-local exclusive
    if (threadIdx.x == 255) bsum[blockIdx.x] = sh[255];
}

__global__ __launch_bounds__(256) void k_scan2(int* bsum, int nblocks) {
    __shared__ int sh[256];
    int v = (threadIdx.x < nblocks) ? bsum[threadIdx.x] : 0;
    sh[threadIdx.x] = v;
    __syncthreads();
    for (int off = 1; off < 256; off <<= 1) {
        int t = (threadIdx.x >= off) ? sh[threadIdx.x - off] : 0;
        __syncthreads();
        sh[threadIdx.x] += t;
        __syncthreads();
    }
    if (threadIdx.x < nblocks) bsum[threadIdx.x] = sh[threadIdx.x] - v;  // exclusive
}

// rowptr += block offset; cursor = rowptr; dinv = rsqrt(deg+1)
__global__ __launch_bounds__(256) void k_scan3(int* rowptr, const int* __restrict__ bsum,
                                               const int* __restrict__ degi,
                                               float* dinv, int* cursor) {
    int i = blockIdx.x * 256 + threadIdx.x;
    int r = rowptr[i] + bsum[blockIdx.x];
    rowptr[i] = r;
    cursor[i] = r;
    if (i < N_NODES) dinv[i] = rsqrtf((float)degi[i] + 1.0f);  // +1 self loop
}

// ---------------- CSR fill ----------------
__global__ void k_fill(const int* __restrict__ src, const int* __restrict__ dst,
                       int* cursor, int* csr_src, int nedges) {
    int e = blockIdx.x * 256 + threadIdx.x;
    if (e < nedges) {
        int pos = atomicAdd(&cursor[dst[e]], 1);
        csr_src[pos] = src[e];
    }
}

// ---------------- matmul: T = act(in) @ W ; A = b + T * dinv^2 ----------------
template<bool RELU_IN>
__global__ __launch_bounds__(256) void k_matmul(
    const float* __restrict__ xin, const float* __restrict__ W,
    const float* __restrict__ b, const float* __restrict__ dinv,
    float* __restrict__ T, float* A)
{
    __shared__ float Wl[DIM * DIM];   // 64 KB
    __shared__ float Xl[32 * DIM];    // 16 KB

    const int tid = threadIdx.x;
    const int rowbase = blockIdx.x * 32;

    #pragma unroll
    for (int i = 0; i < 16; ++i) {
        int idx4 = tid + i * 256;
        ((float4*)Wl)[idx4] = ((const float4*)W)[idx4];
    }
    #pragma unroll
    for (int i = 0; i < 4; ++i) {
        int idx4 = tid + i * 256;
        int row  = idx4 >> 5;
        int grow = rowbase + row;
        float4 f = make_float4(0.f, 0.f, 0.f, 0.f);
        if (grow < N_NODES) {
            f = ((const float4*)xin)[rowbase * 32 + idx4];
            if (RELU_IN) {
                f.x = fmaxf(f.x, 0.f); f.y = fmaxf(f.y, 0.f);
                f.z = fmaxf(f.z, 0.f); f.w = fmaxf(f.w, 0.f);
            }
        }
        ((float4*)Xl)[idx4] = f;
    }
    __syncthreads();

    const int cg = tid & 31;
    const int r0 = (tid >> 5) * 4;

    float acc[4][4];
    #pragma unroll
    for (int i = 0; i < 4; ++i)
        #pragma unroll
        for (int j = 0; j < 4; ++j) acc[i][j] = 0.f;

    for (int k = 0; k < DIM; ++k) {
        float4 w = ((float4*)Wl)[k * 32 + cg];
        #pragma unroll
        for (int i = 0; i < 4; ++i) {
            float xv = Xl[(r0 + i) * DIM + k];
            acc[i][0] += xv * w.x;
            acc[i][1] += xv * w.y;
            acc[i][2] += xv * w.z;
            acc[i][3] += xv * w.w;
        }
    }

    float4 bv = ((const float4*)b)[cg];

    #pragma unroll
    for (int i = 0; i < 4; ++i) {
        int n = rowbase + r0 + i;
        if (n < N_NODES) {
            float di = dinv[n];
            float sl = di * di;
            float4 t = make_float4(acc[i][0], acc[i][1], acc[i][2], acc[i][3]);
            ((float4*)(T + (long long)n * DIM))[cg] = t;
            float4 a = make_float4(bv.x + t.x * sl, bv.y + t.y * sl,
                                   bv.z + t.z * sl, bv.w + t.w * sl);
            ((float4*)(A + (long long)n * DIM))[cg] = a;
        }
    }
}

// ---------------- gather: A[d,:] += sum_e T[src_e,:] * dinv[src]*dinv[d] ----------------
// 2 nodes per 256-thread block, 128 threads (one feature each) per node. No atomics.
__global__ __launch_bounds__(256) void k_gather(
    const int* __restrict__ rowptr, const int* __restrict__ csr_src,
    const float* __restrict__ dinv, const float* __restrict__ T,
    float* A)
{
    int node = blockIdx.x * 2 + (threadIdx.x >> 7);
    int j = threadIdx.x & 127;
    if (node >= N_NODES) return;
    int p0 = rowptr[node];
    int p1 = rowptr[node + 1];
    float dd = dinv[node];
    float acc = A[(long long)node * DIM + j];
    for (int p = p0; p < p1; ++p) {
        int s = csr_src[p];
        acc += T[(long long)s * DIM + j] * (dinv[s] * dd);
    }
    A[(long long)node * DIM + j] = acc;
}

// ---------------- pooling: run-length accumulate over sorted batch ----------------
#define NPB 512
__global__ __launch_bounds__(128) void k_pool(
    const float* __restrict__ h, const int* __restrict__ batch,
    float* pooled, float* counts)
{
    int j = threadIdx.x;
    int n0 = blockIdx.x * NPB;
    if (n0 >= N_NODES) return;
    int nend = min(n0 + NPB, N_NODES);
    int cur = batch[n0];
    int runstart = n0;
    float acc = 0.f;
    for (int n = n0; n < nend; ++n) {
        int g = batch[n];
        if (g != cur) {
            atomicAdd(&pooled[cur * DIM + j], acc);
            if (j == 0) atomicAdd(&counts[cur], (float)(n - runstart));
            acc = 0.f; cur = g; runstart = n;
        }
        acc += h[(long long)n * DIM + j];
    }
    atomicAdd(&pooled[cur * DIM + j], acc);
    if (j == 0) atomicAdd(&counts[cur], (float)(nend - runstart));
}

// ---------------- classifier head ----------------
__global__ __launch_bounds__(128) void k_cls(
    const float* __restrict__ pooled, const float* __restrict__ counts,
    const float* __restrict__ C1, const float* __restrict__ bc1,
    const float* __restrict__ C2, const float* __restrict__ bc2,
    float* out)
{
    __shared__ float pm[DIM];
    __shared__ float gv[DIM];
    int g = blockIdx.x, j = threadIdx.x;
    float cnt = fmaxf(counts[g], 1.0f);
    pm[j] = pooled[g * DIM + j] / cnt;
    __syncthreads();
    float a = bc1[j];
    for (int k = 0; k < DIM; ++k) a += pm[k] * C1[k * DIM + j];
    gv[j] = fmaxf(a, 0.f);
    __syncthreads();
    if (j < NUM_CLASSES) {
        float o = bc2[j];
        for (int k = 0; k < DIM; ++k) o += gv[k] * C2[k * NUM_CLASSES + j];
        out[g * NUM_CLASSES + j] = o;
    }
}

extern "C" void kernel_launch(void* const* d_in, const int* in_sizes, int n_in,
                              void* d_out, int out_size, void* d_ws, size_t ws_size,
                              hipStream_t stream) {
    const float* x    = (const float*)d_in[0];
    const int*   ei   = (const int*)d_in[1];
    const int*   batch= (const int*)d_in[2];
    const float* W1   = (const float*)d_in[3];
    const float* b1   = (const float*)d_in[4];
    const float* W2   = (const float*)d_in[5];
    const float* b2   = (const float*)d_in[6];
    const float* W3   = (const float*)d_in[7];
    const float* b3   = (const float*)d_in[8];
    const float* C1   = (const float*)d_in[9];
    const float* bc1  = (const float*)d_in[10];
    const float* C2   = (const float*)d_in[11];
    const float* bc2  = (const float*)d_in[12];

    const int nedges = in_sizes[1] / 2;
    const int* src = ei;
    const int* dst = ei + nedges;

    // workspace layout (4-byte units)
    float* dinv    = (float*)d_ws;                         // NPAD
    float* T       = dinv + NPAD;                          // 6.4M
    float* A       = T + (long long)N_NODES * DIM;         // 6.4M
    float* pooled  = A + (long long)N_NODES * DIM;         // 8192
    float* counts  = pooled + NUM_GRAPHS * DIM;            // 64
    int*   degi    = (int*)(counts + 64);                  // NPAD
    int*   rowptr  = degi + NPAD;                          // NPAD+256 (need N_NODES+1)
    int*   cursor  = rowptr + NPAD + 256;                  // NPAD
    int*   bsum    = cursor + NPAD;                        // 256
    int*   csr_src = bsum + 256;                           // nedges

    const int nodeBlocks = NPAD / 256;                     // 196
    const int mmBlocks   = (N_NODES + 31) / 32;            // 1563
    const int edgeBlocks = (nedges + 255) / 256;           // 3125
    const int gBlocks    = (N_NODES + 1) / 2;              // 25000
    const int poolBlocks = (N_NODES + NPB - 1) / NPB;      // 98

    // CSR build + norm
    k_init<<<nodeBlocks, 256, 0, stream>>>(degi, pooled, counts);
    k_count<<<edgeBlocks, 256, 0, stream>>>(dst, degi, nedges);
    k_scan1<<<nodeBlocks, 256, 0, stream>>>(degi, rowptr, bsum);
    k_scan2<<<1, 256, 0, stream>>>(bsum, nodeBlocks);
    k_scan3<<<nodeBlocks, 256, 0, stream>>>(rowptr, bsum, degi, dinv, cursor);
    k_fill<<<edgeBlocks, 256, 0, stream>>>(src, dst, cursor, csr_src, nedges);

    // layer 1
    k_matmul<false><<<mmBlocks, 256, 0, stream>>>(x, W1, b1, dinv, T, A);
    k_gather<<<gBlocks, 256, 0, stream>>>(rowptr, csr_src, dinv, T, A);
    // layer 2
    k_matmul<true><<<mmBlocks, 256, 0, stream>>>(A, W2, b2, dinv, T, A);
    k_gather<<<gBlocks, 256, 0, stream>>>(rowptr, csr_src, dinv, T, A);
    // layer 3
    k_matmul<true><<<mmBlocks, 256, 0, stream>>>(A, W3, b3, dinv, T, A);
    k_gather<<<gBlocks, 256, 0, stream>>>(rowptr, csr_src, dinv, T, A);

    k_pool<<<poolBlocks, 128, 0, stream>>>(A, batch, pooled, counts);
    k_cls<<<NUM_GRAPHS, 128, 0, stream>>>(pooled, counts, C1, bc1, C2, bc2,
                                          (float*)d_out);
}

// Round 4
// 549.597 us; speedup vs baseline: 2.5654x; 1.5620x over previous
//
#include <hip/hip_runtime.h>
#include <hip/hip_bf16.h>

#define N_NODES    50000
#define DIM        128
#define NUM_GRAPHS 64
#define NUM_CLASSES 3
#define NPAD       50176   // 196*256, padded node count

typedef unsigned short ushort_t;
typedef unsigned int   uint_t;

__device__ __forceinline__ ushort_t f2bf(float f) {
    union { float f; uint_t u; } v; v.f = f;
    uint_t r = v.u + 0x7fffu + ((v.u >> 16) & 1u);   // RNE
    return (ushort_t)(r >> 16);
}
__device__ __forceinline__ float bflo(uint_t u) {   // low ushort of packed pair
    union { uint_t u; float f; } v; v.u = u << 16; return v.f;
}
__device__ __forceinline__ float bfhi(uint_t u) {   // high ushort of packed pair
    union { uint_t u; float f; } v; v.u = u & 0xffff0000u; return v.f;
}

// ---------------- init: degi=0, pooled=0, counts=0 ----------------
__global__ void k_init(int* degi, float* pooled, float* counts) {
    int i = blockIdx.x * 256 + threadIdx.x;
    if (i < NPAD) degi[i] = 0;
    if (i < NUM_GRAPHS * DIM) pooled[i] = 0.0f;
    if (i < NUM_GRAPHS) counts[i] = 0.0f;
}

// ---------------- in-degree histogram ----------------
__global__ void k_count(const int* __restrict__ dst, int* degi, int nedges) {
    int e = blockIdx.x * 256 + threadIdx.x;
    if (e < nedges) atomicAdd(&degi[dst[e]], 1);
}

// ---------------- 3-phase exclusive scan over NPAD entries ----------------
__global__ __launch_bounds__(256) void k_scan1(const int* __restrict__ degi,
                                               int* rowptr, int* bsum) {
    __shared__ int sh[256];
    int i = blockIdx.x * 256 + threadIdx.x;
    int v = degi[i];
    sh[threadIdx.x] = v;
    __syncthreads();
    for (int off = 1; off < 256; off <<= 1) {
        int t = (threadIdx.x >= off) ? sh[threadIdx.x - off] : 0;
        __syncthreads();
        sh[threadIdx.x] += t;
        __syncthreads();
    }
    rowptr[i] = sh[threadIdx.x] - v;
    if (threadIdx.x == 255) bsum[blockIdx.x] = sh[255];
}

__global__ __launch_bounds__(256) void k_scan2(int* bsum, int nblocks) {
    __shared__ int sh[256];
    int v = (threadIdx.x < nblocks) ? bsum[threadIdx.x] : 0;
    sh[threadIdx.x] = v;
    __syncthreads();
    for (int off = 1; off < 256; off <<= 1) {
        int t = (threadIdx.x >= off) ? sh[threadIdx.x - off] : 0;
        __syncthreads();
        sh[threadIdx.x] += t;
        __syncthreads();
    }
    if (threadIdx.x < nblocks) bsum[threadIdx.x] = sh[threadIdx.x] - v;
}

__global__ __launch_bounds__(256) void k_scan3(int* rowptr, const int* __restrict__ bsum,
                                               const int* __restrict__ degi,
                                               float* dinv, int* cursor) {
    int i = blockIdx.x * 256 + threadIdx.x;
    int r = rowptr[i] + bsum[blockIdx.x];
    rowptr[i] = r;
    cursor[i] = r;
    if (i < N_NODES) dinv[i] = rsqrtf((float)degi[i] + 1.0f);
}

// ---------------- CSR fill ----------------
__global__ void k_fill(const int* __restrict__ src, const int* __restrict__ dst,
                       int* cursor, int* csr_src, int nedges) {
    int e = blockIdx.x * 256 + threadIdx.x;
    if (e < nedges) {
        int pos = atomicAdd(&cursor[dst[e]], 1);
        csr_src[pos] = src[e];
    }
}

// ---------------- matmul: Tb(bf16) = act(in) @ W ; A = b + T * dinv^2 ----------------
// Block: 256 threads, 32 rows. W fp32 LDS (64 KB) + X fp32 LDS (16 KB) = 80 KB.
// Inner loop k-blocked by 4: all LDS reads are ds_read_b128.
template<bool RELU_IN>
__global__ __launch_bounds__(256) void k_matmul(
    const float* __restrict__ xin, const float* __restrict__ W,
    const float* __restrict__ b, const float* __restrict__ dinv,
    ushort_t* __restrict__ Tb, float* A)
{
    __shared__ float Wl[DIM * DIM];   // 64 KB
    __shared__ float Xl[32 * DIM];    // 16 KB

    const int tid = threadIdx.x;
    const int rowbase = blockIdx.x * 32;

    #pragma unroll
    for (int i = 0; i < 16; ++i) {
        int idx4 = tid + i * 256;
        ((float4*)Wl)[idx4] = ((const float4*)W)[idx4];
    }
    #pragma unroll
    for (int i = 0; i < 4; ++i) {
        int idx4 = tid + i * 256;
        int row  = idx4 >> 5;
        int grow = rowbase + row;
        float4 f = make_float4(0.f, 0.f, 0.f, 0.f);
        if (grow < N_NODES) {
            f = ((const float4*)xin)[rowbase * 32 + idx4];
            if (RELU_IN) {
                f.x = fmaxf(f.x, 0.f); f.y = fmaxf(f.y, 0.f);
                f.z = fmaxf(f.z, 0.f); f.w = fmaxf(f.w, 0.f);
            }
        }
        ((float4*)Xl)[idx4] = f;
    }
    __syncthreads();

    const int cg = tid & 31;
    const int r0 = (tid >> 5) * 4;

    float acc[4][4];
    #pragma unroll
    for (int i = 0; i < 4; ++i)
        #pragma unroll
        for (int j = 0; j < 4; ++j) acc[i][j] = 0.f;

    for (int kc = 0; kc < DIM; kc += 4) {
        float4 xv[4], wv[4];
        #pragma unroll
        for (int i = 0; i < 4; ++i)
            xv[i] = ((float4*)Xl)[(r0 + i) * 32 + (kc >> 2)];
        #pragma unroll
        for (int q = 0; q < 4; ++q)
            wv[q] = ((float4*)Wl)[(kc + q) * 32 + cg];
        #pragma unroll
        for (int i = 0; i < 4; ++i) {
            float x0 = xv[i].x, x1 = xv[i].y, x2 = xv[i].z, x3 = xv[i].w;
            acc[i][0] += x0*wv[0].x + x1*wv[1].x + x2*wv[2].x + x3*wv[3].x;
            acc[i][1] += x0*wv[0].y + x1*wv[1].y + x2*wv[2].y + x3*wv[3].y;
            acc[i][2] += x0*wv[0].z + x1*wv[1].z + x2*wv[2].z + x3*wv[3].z;
            acc[i][3] += x0*wv[0].w + x1*wv[1].w + x2*wv[2].w + x3*wv[3].w;
        }
    }

    float4 bv = ((const float4*)b)[cg];

    #pragma unroll
    for (int i = 0; i < 4; ++i) {
        int n = rowbase + r0 + i;
        if (n < N_NODES) {
            float di = dinv[n];
            float sl = di * di;
            ushort4 tb;
            tb.x = f2bf(acc[i][0]); tb.y = f2bf(acc[i][1]);
            tb.z = f2bf(acc[i][2]); tb.w = f2bf(acc[i][3]);
            ((ushort4*)(Tb + (long long)n * DIM))[cg] = tb;
            float4 a = make_float4(bv.x + acc[i][0] * sl, bv.y + acc[i][1] * sl,
                                   bv.z + acc[i][2] * sl, bv.w + acc[i][3] * sl);
            ((float4*)(A + (long long)n * DIM))[cg] = a;
        }
    }
}

// ---------------- gather: A[d,:] += sum_e T[src_e,:] * dinv[src]*dinv[d] ----------------
// One wave per node: 64 lanes x ushort2 = one 256B coalesced row read. 4x unrolled.
__global__ __launch_bounds__(256) void k_gather(
    const int* __restrict__ rowptr, const int* __restrict__ csr_src,
    const float* __restrict__ dinv, const uint_t* __restrict__ Tb,
    float* A)
{
    int node = blockIdx.x * 4 + (threadIdx.x >> 6);
    int j2 = threadIdx.x & 63;          // feature-pair index
    int p0 = rowptr[node];
    int p1 = rowptr[node + 1];
    float dd = dinv[node];
    float2 acc = ((float2*)A)[node * 64 + j2];
    int p = p0;
    for (; p + 4 <= p1; p += 4) {
        int s0 = csr_src[p + 0];
        int s1 = csr_src[p + 1];
        int s2 = csr_src[p + 2];
        int s3 = csr_src[p + 3];
        uint_t u0 = Tb[s0 * 64 + j2];
        uint_t u1 = Tb[s1 * 64 + j2];
        uint_t u2 = Tb[s2 * 64 + j2];
        uint_t u3 = Tb[s3 * 64 + j2];
        float w0 = dinv[s0] * dd;
        float w1 = dinv[s1] * dd;
        float w2 = dinv[s2] * dd;
        float w3 = dinv[s3] * dd;
        acc.x += bflo(u0) * w0; acc.y += bfhi(u0) * w0;
        acc.x += bflo(u1) * w1; acc.y += bfhi(u1) * w1;
        acc.x += bflo(u2) * w2; acc.y += bfhi(u2) * w2;
        acc.x += bflo(u3) * w3; acc.y += bfhi(u3) * w3;
    }
    for (; p < p1; ++p) {
        int s = csr_src[p];
        uint_t u = Tb[s * 64 + j2];
        float w = dinv[s] * dd;
        acc.x += bflo(u) * w; acc.y += bfhi(u) * w;
    }
    ((float2*)A)[node * 64 + j2] = acc;
}

// ---------------- pooling: run-length accumulate over sorted batch ----------------
#define NPB 512
__global__ __launch_bounds__(128) void k_pool(
    const float* __restrict__ h, const int* __restrict__ batch,
    float* pooled, float* counts)
{
    int j = threadIdx.x;
    int n0 = blockIdx.x * NPB;
    if (n0 >= N_NODES) return;
    int nend = min(n0 + NPB, N_NODES);
    int cur = batch[n0];
    int runstart = n0;
    float acc = 0.f;
    for (int n = n0; n < nend; ++n) {
        int g = batch[n];
        if (g != cur) {
            atomicAdd(&pooled[cur * DIM + j], acc);
            if (j == 0) atomicAdd(&counts[cur], (float)(n - runstart));
            acc = 0.f; cur = g; runstart = n;
        }
        acc += h[(long long)n * DIM + j];
    }
    atomicAdd(&pooled[cur * DIM + j], acc);
    if (j == 0) atomicAdd(&counts[cur], (float)(nend - runstart));
}

// ---------------- classifier head ----------------
__global__ __launch_bounds__(128) void k_cls(
    const float* __restrict__ pooled, const float* __restrict__ counts,
    const float* __restrict__ C1, const float* __restrict__ bc1,
    const float* __restrict__ C2, const float* __restrict__ bc2,
    float* out)
{
    __shared__ float pm[DIM];
    __shared__ float gv[DIM];
    int g = blockIdx.x, j = threadIdx.x;
    float cnt = fmaxf(counts[g], 1.0f);
    pm[j] = pooled[g * DIM + j] / cnt;
    __syncthreads();
    float a = bc1[j];
    for (int k = 0; k < DIM; ++k) a += pm[k] * C1[k * DIM + j];
    gv[j] = fmaxf(a, 0.f);
    __syncthreads();
    if (j < NUM_CLASSES) {
        float o = bc2[j];
        for (int k = 0; k < DIM; ++k) o += gv[k] * C2[k * NUM_CLASSES + j];
        out[g * NUM_CLASSES + j] = o;
    }
}

extern "C" void kernel_launch(void* const* d_in, const int* in_sizes, int n_in,
                              void* d_out, int out_size, void* d_ws, size_t ws_size,
                              hipStream_t stream) {
    const float* x    = (const float*)d_in[0];
    const int*   ei   = (const int*)d_in[1];
    const int*   batch= (const int*)d_in[2];
    const float* W1   = (const float*)d_in[3];
    const float* b1   = (const float*)d_in[4];
    const float* W2   = (const float*)d_in[5];
    const float* b2   = (const float*)d_in[6];
    const float* W3   = (const float*)d_in[7];
    const float* b3   = (const float*)d_in[8];
    const float* C1   = (const float*)d_in[9];
    const float* bc1  = (const float*)d_in[10];
    const float* C2   = (const float*)d_in[11];
    const float* bc2  = (const float*)d_in[12];

    const int nedges = in_sizes[1] / 2;
    const int* src = ei;
    const int* dst = ei + nedges;

    // workspace layout (4-byte units)
    float*    dinv    = (float*)d_ws;                          // NPAD
    uint_t*   Tb      = (uint_t*)(dinv + NPAD);                // N_NODES*64 uints (bf16 pairs)
    float*    A       = (float*)(Tb + (long long)N_NODES*64);  // 6.4M
    float*    pooled  = A + (long long)N_NODES * DIM;          // 8192
    float*    counts  = pooled + NUM_GRAPHS * DIM;             // 64
    int*      degi    = (int*)(counts + 64);                   // NPAD
    int*      rowptr  = degi + NPAD;                           // NPAD+256
    int*      cursor  = rowptr + NPAD + 256;                   // NPAD
    int*      bsum    = cursor + NPAD;                         // 256
    int*      csr_src = bsum + 256;                            // nedges

    const int nodeBlocks = NPAD / 256;                     // 196
    const int mmBlocks   = (N_NODES + 31) / 32;            // 1563
    const int edgeBlocks = (nedges + 255) / 256;           // 3125
    const int gBlocks    = (N_NODES + 3) / 4;              // 12500
    const int poolBlocks = (N_NODES + NPB - 1) / NPB;      // 98

    // CSR build + norm
    k_init<<<nodeBlocks, 256, 0, stream>>>(degi, pooled, counts);
    k_count<<<edgeBlocks, 256, 0, stream>>>(dst, degi, nedges);
    k_scan1<<<nodeBlocks, 256, 0, stream>>>(degi, rowptr, bsum);
    k_scan2<<<1, 256, 0, stream>>>(bsum, nodeBlocks);
    k_scan3<<<nodeBlocks, 256, 0, stream>>>(rowptr, bsum, degi, dinv, cursor);
    k_fill<<<edgeBlocks, 256, 0, stream>>>(src, dst, cursor, csr_src, nedges);

    // layer 1
    k_matmul<false><<<mmBlocks, 256, 0, stream>>>(x, W1, b1, dinv, (ushort_t*)Tb, A);
    k_gather<<<gBlocks, 256, 0, stream>>>(rowptr, csr_src, dinv, Tb, A);
    // layer 2
    k_matmul<true><<<mmBlocks, 256, 0, stream>>>(A, W2, b2, dinv, (ushort_t*)Tb, A);
    k_gather<<<gBlocks, 256, 0, stream>>>(rowptr, csr_src, dinv, Tb, A);
    // layer 3
    k_matmul<true><<<mmBlocks, 256, 0, stream>>>(A, W3, b3, dinv, (ushort_t*)Tb, A);
    k_gather<<<gBlocks, 256, 0, stream>>>(rowptr, csr_src, dinv, Tb, A);

    k_pool<<<poolBlocks, 128, 0, stream>>>(A, batch, pooled, counts);
    k_cls<<<NUM_GRAPHS, 128, 0, stream>>>(pooled, counts, C1, bc1, C2, bc2,
                                          (float*)d_out);
}

// Round 5
// 426.010 us; speedup vs baseline: 3.3096x; 1.2901x over previous
//
#include <hip/hip_runtime.h>
#include <hip/hip_bf16.h>

#define N_NODES    50000
#define DIM        128
#define NUM_GRAPHS 64
#define NUM_CLASSES 3
#define NPAD       50176   // 196*256, padded node count

typedef unsigned short ushort_t;
typedef unsigned int   uint_t;

__device__ __forceinline__ ushort_t f2bf(float f) {
    union { float f; uint_t u; } v; v.f = f;
    uint_t r = v.u + 0x7fffu + ((v.u >> 16) & 1u);   // RNE
    return (ushort_t)(r >> 16);
}
__device__ __forceinline__ float bflo(uint_t u) {
    union { uint_t u; float f; } v; v.u = u << 16; return v.f;
}
__device__ __forceinline__ float bfhi(uint_t u) {
    union { uint_t u; float f; } v; v.u = u & 0xffff0000u; return v.f;
}

// ---------------- init ----------------
__global__ void k_init(int* degi, float* pooled, float* counts) {
    int i = blockIdx.x * 256 + threadIdx.x;
    if (i < NPAD) degi[i] = 0;
    if (i < NUM_GRAPHS * DIM) pooled[i] = 0.0f;
    if (i < NUM_GRAPHS) counts[i] = 0.0f;
}

__global__ void k_count(const int* __restrict__ dst, int* degi, int nedges) {
    int e = blockIdx.x * 256 + threadIdx.x;
    if (e < nedges) atomicAdd(&degi[dst[e]], 1);
}

// ---------------- scan ----------------
__global__ __launch_bounds__(256) void k_scan1(const int* __restrict__ degi,
                                               int* rowptr, int* bsum) {
    __shared__ int sh[256];
    int i = blockIdx.x * 256 + threadIdx.x;
    int v = degi[i];
    sh[threadIdx.x] = v;
    __syncthreads();
    for (int off = 1; off < 256; off <<= 1) {
        int t = (threadIdx.x >= off) ? sh[threadIdx.x - off] : 0;
        __syncthreads();
        sh[threadIdx.x] += t;
        __syncthreads();
    }
    rowptr[i] = sh[threadIdx.x] - v;
    if (threadIdx.x == 255) bsum[blockIdx.x] = sh[255];
}

__global__ __launch_bounds__(256) void k_scan2(int* bsum, int nblocks) {
    __shared__ int sh[256];
    int v = (threadIdx.x < nblocks) ? bsum[threadIdx.x] : 0;
    sh[threadIdx.x] = v;
    __syncthreads();
    for (int off = 1; off < 256; off <<= 1) {
        int t = (threadIdx.x >= off) ? sh[threadIdx.x - off] : 0;
        __syncthreads();
        sh[threadIdx.x] += t;
        __syncthreads();
    }
    if (threadIdx.x < nblocks) bsum[threadIdx.x] = sh[threadIdx.x] - v;
}

__global__ __launch_bounds__(256) void k_scan3(int* rowptr, const int* __restrict__ bsum,
                                               const int* __restrict__ degi,
                                               float* dinv, int* cursor) {
    int i = blockIdx.x * 256 + threadIdx.x;
    int r = rowptr[i] + bsum[blockIdx.x];
    rowptr[i] = r;
    cursor[i] = r;
    if (i < N_NODES) dinv[i] = rsqrtf((float)degi[i] + 1.0f);
}

__global__ void k_fill(const int* __restrict__ src, const int* __restrict__ dst,
                       int* cursor, int* csr_src, int nedges) {
    int e = blockIdx.x * 256 + threadIdx.x;
    if (e < nedges) {
        int pos = atomicAdd(&cursor[dst[e]], 1);
        csr_src[pos] = src[e];
    }
}

// ---------------- matmul: Tb(bf16) = act(in) @ W ; A = b + T * dinv^2 ----------------
template<bool RELU_IN>
__global__ __launch_bounds__(256) void k_matmul(
    const float* __restrict__ xin, const float* __restrict__ W,
    const float* __restrict__ b, const float* __restrict__ dinv,
    ushort_t* __restrict__ Tb, float* A)
{
    __shared__ float Wl[DIM * DIM];
    __shared__ float Xl[32 * DIM];

    const int tid = threadIdx.x;
    const int rowbase = blockIdx.x * 32;

    #pragma unroll
    for (int i = 0; i < 16; ++i) {
        int idx4 = tid + i * 256;
        ((float4*)Wl)[idx4] = ((const float4*)W)[idx4];
    }
    #pragma unroll
    for (int i = 0; i < 4; ++i) {
        int idx4 = tid + i * 256;
        int row  = idx4 >> 5;
        int grow = rowbase + row;
        float4 f = make_float4(0.f, 0.f, 0.f, 0.f);
        if (grow < N_NODES) {
            f = ((const float4*)xin)[rowbase * 32 + idx4];
            if (RELU_IN) {
                f.x = fmaxf(f.x, 0.f); f.y = fmaxf(f.y, 0.f);
                f.z = fmaxf(f.z, 0.f); f.w = fmaxf(f.w, 0.f);
            }
        }
        ((float4*)Xl)[idx4] = f;
    }
    __syncthreads();

    const int cg = tid & 31;
    const int r0 = (tid >> 5) * 4;

    float acc[4][4];
    #pragma unroll
    for (int i = 0; i < 4; ++i)
        #pragma unroll
        for (int j = 0; j < 4; ++j) acc[i][j] = 0.f;

    for (int kc = 0; kc < DIM; kc += 4) {
        float4 xv[4], wv[4];
        #pragma unroll
        for (int i = 0; i < 4; ++i)
            xv[i] = ((float4*)Xl)[(r0 + i) * 32 + (kc >> 2)];
        #pragma unroll
        for (int q = 0; q < 4; ++q)
            wv[q] = ((float4*)Wl)[(kc + q) * 32 + cg];
        #pragma unroll
        for (int i = 0; i < 4; ++i) {
            float x0 = xv[i].x, x1 = xv[i].y, x2 = xv[i].z, x3 = xv[i].w;
            acc[i][0] += x0*wv[0].x + x1*wv[1].x + x2*wv[2].x + x3*wv[3].x;
            acc[i][1] += x0*wv[0].y + x1*wv[1].y + x2*wv[2].y + x3*wv[3].y;
            acc[i][2] += x0*wv[0].z + x1*wv[1].z + x2*wv[2].z + x3*wv[3].z;
            acc[i][3] += x0*wv[0].w + x1*wv[1].w + x2*wv[2].w + x3*wv[3].w;
        }
    }

    float4 bv = ((const float4*)b)[cg];

    #pragma unroll
    for (int i = 0; i < 4; ++i) {
        int n = rowbase + r0 + i;
        if (n < N_NODES) {
            float di = dinv[n];
            float sl = di * di;
            ushort4 tb;
            tb.x = f2bf(acc[i][0]); tb.y = f2bf(acc[i][1]);
            tb.z = f2bf(acc[i][2]); tb.w = f2bf(acc[i][3]);
            ((ushort4*)(Tb + (long long)n * DIM))[cg] = tb;
            float4 a = make_float4(bv.x + acc[i][0] * sl, bv.y + acc[i][1] * sl,
                                   bv.z + acc[i][2] * sl, bv.w + acc[i][3] * sl);
            ((float4*)(A + (long long)n * DIM))[cg] = a;
        }
    }
}

// ---------------- gather: one wave per node, 8x unrolled edge loop ----------------
__global__ __launch_bounds__(256) void k_gather(
    const int* __restrict__ rowptr, const int* __restrict__ csr_src,
    const float* __restrict__ dinv, const uint_t* __restrict__ Tb,
    float* A)
{
    int node = blockIdx.x * 4 + (threadIdx.x >> 6);
    int j2 = threadIdx.x & 63;
    int p0 = rowptr[node];
    int p1 = rowptr[node + 1];
    float dd = dinv[node];
    float2 acc = ((float2*)A)[node * 64 + j2];
    int p = p0;
    for (; p + 8 <= p1; p += 8) {
        int s[8]; uint_t u[8]; float w[8];
        #pragma unroll
        for (int q = 0; q < 8; ++q) s[q] = csr_src[p + q];
        #pragma unroll
        for (int q = 0; q < 8; ++q) u[q] = Tb[s[q] * 64 + j2];
        #pragma unroll
        for (int q = 0; q < 8; ++q) w[q] = dinv[s[q]] * dd;
        #pragma unroll
        for (int q = 0; q < 8; ++q) {
            acc.x += bflo(u[q]) * w[q];
            acc.y += bfhi(u[q]) * w[q];
        }
    }
    for (; p + 4 <= p1; p += 4) {
        int s[4]; uint_t u[4]; float w[4];
        #pragma unroll
        for (int q = 0; q < 4; ++q) s[q] = csr_src[p + q];
        #pragma unroll
        for (int q = 0; q < 4; ++q) u[q] = Tb[s[q] * 64 + j2];
        #pragma unroll
        for (int q = 0; q < 4; ++q) w[q] = dinv[s[q]] * dd;
        #pragma unroll
        for (int q = 0; q < 4; ++q) {
            acc.x += bflo(u[q]) * w[q];
            acc.y += bfhi(u[q]) * w[q];
        }
    }
    for (; p < p1; ++p) {
        int s = csr_src[p];
        uint_t u = Tb[s * 64 + j2];
        float w = dinv[s] * dd;
        acc.x += bflo(u) * w; acc.y += bfhi(u) * w;
    }
    ((float2*)A)[node * 64 + j2] = acc;
}

// ---------------- pooling: 64 nodes per block, 782 blocks ----------------
#define NPB 64
__global__ __launch_bounds__(128) void k_pool(
    const float* __restrict__ h, const int* __restrict__ batch,
    float* pooled, float* counts)
{
    int j = threadIdx.x;
    int n0 = blockIdx.x * NPB;
    if (n0 >= N_NODES) return;
    int nend = min(n0 + NPB, N_NODES);
    int cur = batch[n0];
    int runstart = n0;
    float acc = 0.f;
    for (int n = n0; n < nend; ++n) {
        int g = batch[n];
        if (g != cur) {
            atomicAdd(&pooled[cur * DIM + j], acc);
            if (j == 0) atomicAdd(&counts[cur], (float)(n - runstart));
            acc = 0.f; cur = g; runstart = n;
        }
        acc += h[(long long)n * DIM + j];
    }
    atomicAdd(&pooled[cur * DIM + j], acc);
    if (j == 0) atomicAdd(&counts[cur], (float)(nend - runstart));
}

// ---------------- classifier head ----------------
__global__ __launch_bounds__(128) void k_cls(
    const float* __restrict__ pooled, const float* __restrict__ counts,
    const float* __restrict__ C1, const float* __restrict__ bc1,
    const float* __restrict__ C2, const float* __restrict__ bc2,
    float* out)
{
    __shared__ float pm[DIM];
    __shared__ float gv[DIM];
    int g = blockIdx.x, j = threadIdx.x;
    float cnt = fmaxf(counts[g], 1.0f);
    pm[j] = pooled[g * DIM + j] / cnt;
    __syncthreads();
    float a = bc1[j];
    for (int k = 0; k < DIM; ++k) a += pm[k] * C1[k * DIM + j];
    gv[j] = fmaxf(a, 0.f);
    __syncthreads();
    if (j < NUM_CLASSES) {
        float o = bc2[j];
        for (int k = 0; k < DIM; ++k) o += gv[k] * C2[k * NUM_CLASSES + j];
        out[g * NUM_CLASSES + j] = o;
    }
}

extern "C" void kernel_launch(void* const* d_in, const int* in_sizes, int n_in,
                              void* d_out, int out_size, void* d_ws, size_t ws_size,
                              hipStream_t stream) {
    const float* x    = (const float*)d_in[0];
    const int*   ei   = (const int*)d_in[1];
    const int*   batch= (const int*)d_in[2];
    const float* W1   = (const float*)d_in[3];
    const float* b1   = (const float*)d_in[4];
    const float* W2   = (const float*)d_in[5];
    const float* b2   = (const float*)d_in[6];
    const float* W3   = (const float*)d_in[7];
    const float* b3   = (const float*)d_in[8];
    const float* C1   = (const float*)d_in[9];
    const float* bc1  = (const float*)d_in[10];
    const float* C2   = (const float*)d_in[11];
    const float* bc2  = (const float*)d_in[12];

    const int nedges = in_sizes[1] / 2;
    const int* src = ei;
    const int* dst = ei + nedges;

    // workspace layout (4-byte units)
    float*    dinv    = (float*)d_ws;                          // NPAD
    uint_t*   Tb      = (uint_t*)(dinv + NPAD);                // N_NODES*64
    float*    A       = (float*)(Tb + (long long)N_NODES*64);  // 6.4M
    float*    pooled  = A + (long long)N_NODES * DIM;          // 8192
    float*    counts  = pooled + NUM_GRAPHS * DIM;             // 64
    int*      degi    = (int*)(counts + 64);                   // NPAD
    int*      rowptr  = degi + NPAD;                           // NPAD+256
    int*      cursor  = rowptr + NPAD + 256;                   // NPAD
    int*      bsum    = cursor + NPAD;                         // 256
    int*      csr_src = bsum + 256;                            // nedges

    const int nodeBlocks = NPAD / 256;                     // 196
    const int mmBlocks   = (N_NODES + 31) / 32;            // 1563
    const int edgeBlocks = (nedges + 255) / 256;           // 3125
    const int gBlocks    = (N_NODES + 3) / 4;              // 12500
    const int poolBlocks = (N_NODES + NPB - 1) / NPB;      // 782

    k_init<<<nodeBlocks, 256, 0, stream>>>(degi, pooled, counts);
    k_count<<<edgeBlocks, 256, 0, stream>>>(dst, degi, nedges);
    k_scan1<<<nodeBlocks, 256, 0, stream>>>(degi, rowptr, bsum);
    k_scan2<<<1, 256, 0, stream>>>(bsum, nodeBlocks);
    k_scan3<<<nodeBlocks, 256, 0, stream>>>(rowptr, bsum, degi, dinv, cursor);
    k_fill<<<edgeBlocks, 256, 0, stream>>>(src, dst, cursor, csr_src, nedges);

    k_matmul<false><<<mmBlocks, 256, 0, stream>>>(x, W1, b1, dinv, (ushort_t*)Tb, A);
    k_gather<<<gBlocks, 256, 0, stream>>>(rowptr, csr_src, dinv, Tb, A);
    k_matmul<true><<<mmBlocks, 256, 0, stream>>>(A, W2, b2, dinv, (ushort_t*)Tb, A);
    k_gather<<<gBlocks, 256, 0, stream>>>(rowptr, csr_src, dinv, Tb, A);
    k_matmul<true><<<mmBlocks, 256, 0, stream>>>(A, W3, b3, dinv, (ushort_t*)Tb, A);
    k_gather<<<gBlocks, 256, 0, stream>>>(rowptr, csr_src, dinv, Tb, A);

    k_pool<<<poolBlocks, 128, 0, stream>>>(A, batch, pooled, counts);
    k_cls<<<NUM_GRAPHS, 128, 0, stream>>>(pooled, counts, C1, bc1, C2, bc2,
                                          (float*)d_out);
}

// Round 6
// 346.561 us; speedup vs baseline: 4.0683x; 1.2293x over previous
//
#include <hip/hip_runtime.h>
#include <hip/hip_bf16.h>

#define N_NODES    50000
#define DIM        128
#define NUM_GRAPHS 64
#define NUM_CLASSES 3
#define NPAD       50176   // 196*256
#define XPITCH     136     // LDS row pitch in ushorts (17 x 16B granules, odd -> conflict-free b128)

typedef unsigned short ushort_t;
typedef unsigned int   uint_t;
typedef __attribute__((ext_vector_type(8))) short short8;
typedef __attribute__((ext_vector_type(4))) float f32x4;

__device__ __forceinline__ ushort_t f2bf(float f) {
    union { float f; uint_t u; } v; v.f = f;
    uint_t r = v.u + 0x7fffu + ((v.u >> 16) & 1u);   // RNE
    return (ushort_t)(r >> 16);
}
__device__ __forceinline__ float bflo(uint_t u) {
    union { uint_t u; float f; } v; v.u = u << 16; return v.f;
}
__device__ __forceinline__ float bfhi(uint_t u) {
    union { uint_t u; float f; } v; v.u = u & 0xffff0000u; return v.f;
}

// ---------------- init ----------------
__global__ void k_init(int* degi, float* pooled, float* counts) {
    int i = blockIdx.x * 256 + threadIdx.x;
    if (i < NPAD) degi[i] = 0;
    if (i < NUM_GRAPHS * DIM) pooled[i] = 0.0f;
    if (i < NUM_GRAPHS) counts[i] = 0.0f;
}

// ---------------- W -> Wt bf16 transpose (all 3 layers) ----------------
__global__ void k_prep(const float* __restrict__ W1, const float* __restrict__ W2,
                       const float* __restrict__ W3, ushort_t* __restrict__ Wt) {
    int i = blockIdx.x * 256 + threadIdx.x;   // 3*16384 threads
    int mat = i >> 14;
    int idx = i & 16383;
    const float* W = (mat == 0) ? W1 : (mat == 1) ? W2 : W3;
    int n = idx >> 7, k = idx & 127;
    Wt[mat * 16384 + n * 128 + k] = f2bf(W[k * 128 + n]);
}

// ---------------- degree histogram; atomic return value = within-row rank ----------------
__global__ void k_count(const int* __restrict__ dst, int* degi, int* rank, int nedges) {
    int e = blockIdx.x * 256 + threadIdx.x;
    if (e < nedges) rank[e] = atomicAdd(&degi[dst[e]], 1);
}

// ---------------- scan ----------------
__global__ __launch_bounds__(256) void k_scan1(const int* __restrict__ degi,
                                               int* rowptr, int* bsum) {
    __shared__ int sh[256];
    int i = blockIdx.x * 256 + threadIdx.x;
    int v = degi[i];
    sh[threadIdx.x] = v;
    __syncthreads();
    for (int off = 1; off < 256; off <<= 1) {
        int t = (threadIdx.x >= off) ? sh[threadIdx.x - off] : 0;
        __syncthreads();
        sh[threadIdx.x] += t;
        __syncthreads();
    }
    rowptr[i] = sh[threadIdx.x] - v;
    if (threadIdx.x == 255) bsum[blockIdx.x] = sh[255];
}

__global__ __launch_bounds__(256) void k_scan2(int* bsum, int nblocks) {
    __shared__ int sh[256];
    int v = (threadIdx.x < nblocks) ? bsum[threadIdx.x] : 0;
    sh[threadIdx.x] = v;
    __syncthreads();
    for (int off = 1; off < 256; off <<= 1) {
        int t = (threadIdx.x >= off) ? sh[threadIdx.x - off] : 0;
        __syncthreads();
        sh[threadIdx.x] += t;
        __syncthreads();
    }
    if (threadIdx.x < nblocks) bsum[threadIdx.x] = sh[threadIdx.x] - v;
}

__global__ __launch_bounds__(256) void k_scan3(int* rowptr, const int* __restrict__ bsum,
                                               const int* __restrict__ degi,
                                               float* dinv) {
    int i = blockIdx.x * 256 + threadIdx.x;
    rowptr[i] = rowptr[i] + bsum[blockIdx.x];
    if (i < N_NODES) dinv[i] = rsqrtf((float)degi[i] + 1.0f);
}

// ---------------- CSR fill: atomic-free scatter via precomputed rank ----------------
__global__ void k_fill(const int* __restrict__ src, const int* __restrict__ dst,
                       const int* __restrict__ rank, const int* __restrict__ rowptr,
                       int* csr_src, int nedges) {
    int e = blockIdx.x * 256 + threadIdx.x;
    if (e < nedges) csr_src[rowptr[dst[e]] + rank[e]] = src[e];
}

// ---------------- MFMA matmul: Tb(bf16) = act(in) @ W ; A = b + T*dinv^2 ----------------
// Block 256 thr = 4 waves, 64 rows x 128 cols. Xl/Wl bf16 in LDS, pitch 136.
// Wave w: rows m0=w*16..+15. Per n-tile(16): acc over 4 K-steps of 16x16x32 MFMA.
template<bool RELU_IN>
__global__ __launch_bounds__(256) void k_matmul(
    const float* __restrict__ xin, const ushort_t* __restrict__ WtG,
    const float* __restrict__ b, const float* __restrict__ dinv,
    ushort_t* __restrict__ Tb, float* __restrict__ A)
{
    __shared__ ushort_t Wl[DIM * XPITCH];   // 34816 B
    __shared__ ushort_t Xl[64 * XPITCH];    // 17408 B

    const int tid = threadIdx.x;
    const int rowbase = blockIdx.x * 64;

    // stage Wt (dense bf16 [n][k]) -> Wl padded; 2048 x 16B chunks
    #pragma unroll
    for (int i = 0; i < 8; ++i) {
        int g = tid + i * 256;            // chunk id; row=g>>4, colchunk=g&15
        uint4 v = ((const uint4*)WtG)[g];
        *((uint4*)&Wl[(g >> 4) * XPITCH + (g & 15) * 8]) = v;
    }
    // stage X rows (fp32 -> bf16, optional ReLU); 2048 float4 chunks
    #pragma unroll
    for (int i = 0; i < 8; ++i) {
        int c = tid + i * 256;            // float4 id; row=c>>5, col4=c&31
        int row = c >> 5;
        int grow = rowbase + row;
        float4 f = make_float4(0.f, 0.f, 0.f, 0.f);
        if (grow < N_NODES) {
            f = ((const float4*)xin)[(long long)rowbase * 32 + c];
            if (RELU_IN) {
                f.x = fmaxf(f.x, 0.f); f.y = fmaxf(f.y, 0.f);
                f.z = fmaxf(f.z, 0.f); f.w = fmaxf(f.w, 0.f);
            }
        }
        ushort4 h;
        h.x = f2bf(f.x); h.y = f2bf(f.y); h.z = f2bf(f.z); h.w = f2bf(f.w);
        *((ushort4*)&Xl[row * XPITCH + (c & 31) * 4]) = h;
    }
    __syncthreads();

    const int wave = tid >> 6;
    const int lane = tid & 63;
    const int quad = lane >> 4;
    const int lm   = lane & 15;
    const int m0   = wave * 16;

    // A-frags: A[m=lm][k=k0*32 + quad*8 + j], 4 K-steps preloaded
    short8 af[4];
    #pragma unroll
    for (int k0 = 0; k0 < 4; ++k0)
        af[k0] = *(const short8*)&Xl[(m0 + lm) * XPITCH + k0 * 32 + quad * 8];

    // epilogue row data: rows m0 + quad*4 + r
    int noder[4]; float sl[4]; bool okr[4];
    #pragma unroll
    for (int r = 0; r < 4; ++r) {
        int node = rowbase + m0 + quad * 4 + r;
        noder[r] = node;
        okr[r] = (node < N_NODES);
        float di = okr[r] ? dinv[node] : 0.f;
        sl[r] = di * di;
    }

    for (int n0 = 0; n0 < DIM; n0 += 16) {
        f32x4 acc = {0.f, 0.f, 0.f, 0.f};
        #pragma unroll
        for (int k0 = 0; k0 < 4; ++k0) {
            // B[k][n] with n=lm: Wl is [n][k]
            short8 bf = *(const short8*)&Wl[(n0 + lm) * XPITCH + k0 * 32 + quad * 8];
            acc = __builtin_amdgcn_mfma_f32_16x16x32_bf16(af[k0], bf, acc, 0, 0, 0);
        }
        int n = n0 + lm;
        float bias = b[n];
        #pragma unroll
        for (int r = 0; r < 4; ++r) {
            if (okr[r]) {
                float t = acc[r];
                Tb[(long long)noder[r] * DIM + n] = f2bf(t);
                A[(long long)noder[r] * DIM + n] = bias + t * sl[r];
            }
        }
    }
}

// ---------------- gather: one wave per node, 8x unrolled edge loop ----------------
__global__ __launch_bounds__(256) void k_gather(
    const int* __restrict__ rowptr, const int* __restrict__ csr_src,
    const float* __restrict__ dinv, const uint_t* __restrict__ Tb,
    float* A)
{
    int node = blockIdx.x * 4 + (threadIdx.x >> 6);
    int j2 = threadIdx.x & 63;
    int p0 = rowptr[node];
    int p1 = rowptr[node + 1];
    float dd = dinv[node];
    float2 acc = ((float2*)A)[node * 64 + j2];
    int p = p0;
    for (; p + 8 <= p1; p += 8) {
        int s[8]; uint_t u[8]; float w[8];
        #pragma unroll
        for (int q = 0; q < 8; ++q) s[q] = csr_src[p + q];
        #pragma unroll
        for (int q = 0; q < 8; ++q) u[q] = Tb[s[q] * 64 + j2];
        #pragma unroll
        for (int q = 0; q < 8; ++q) w[q] = dinv[s[q]] * dd;
        #pragma unroll
        for (int q = 0; q < 8; ++q) {
            acc.x += bflo(u[q]) * w[q];
            acc.y += bfhi(u[q]) * w[q];
        }
    }
    for (; p + 4 <= p1; p += 4) {
        int s[4]; uint_t u[4]; float w[4];
        #pragma unroll
        for (int q = 0; q < 4; ++q) s[q] = csr_src[p + q];
        #pragma unroll
        for (int q = 0; q < 4; ++q) u[q] = Tb[s[q] * 64 + j2];
        #pragma unroll
        for (int q = 0; q < 4; ++q) w[q] = dinv[s[q]] * dd;
        #pragma unroll
        for (int q = 0; q < 4; ++q) {
            acc.x += bflo(u[q]) * w[q];
            acc.y += bfhi(u[q]) * w[q];
        }
    }
    for (; p < p1; ++p) {
        int s = csr_src[p];
        uint_t u = Tb[s * 64 + j2];
        float w = dinv[s] * dd;
        acc.x += bflo(u) * w; acc.y += bfhi(u) * w;
    }
    ((float2*)A)[node * 64 + j2] = acc;
}

// ---------------- pooling: 64 nodes per block ----------------
#define NPB 64
__global__ __launch_bounds__(128) void k_pool(
    const float* __restrict__ h, const int* __restrict__ batch,
    float* pooled, float* counts)
{
    int j = threadIdx.x;
    int n0 = blockIdx.x * NPB;
    if (n0 >= N_NODES) return;
    int nend = min(n0 + NPB, N_NODES);
    int cur = batch[n0];
    int runstart = n0;
    float acc = 0.f;
    for (int n = n0; n < nend; ++n) {
        int g = batch[n];
        if (g != cur) {
            atomicAdd(&pooled[cur * DIM + j], acc);
            if (j == 0) atomicAdd(&counts[cur], (float)(n - runstart));
            acc = 0.f; cur = g; runstart = n;
        }
        acc += h[(long long)n * DIM + j];
    }
    atomicAdd(&pooled[cur * DIM + j], acc);
    if (j == 0) atomicAdd(&counts[cur], (float)(nend - runstart));
}

// ---------------- classifier head ----------------
__global__ __launch_bounds__(128) void k_cls(
    const float* __restrict__ pooled, const float* __restrict__ counts,
    const float* __restrict__ C1, const float* __restrict__ bc1,
    const float* __restrict__ C2, const float* __restrict__ bc2,
    float* out)
{
    __shared__ float pm[DIM];
    __shared__ float gv[DIM];
    int g = blockIdx.x, j = threadIdx.x;
    float cnt = fmaxf(counts[g], 1.0f);
    pm[j] = pooled[g * DIM + j] / cnt;
    __syncthreads();
    float a = bc1[j];
    for (int k = 0; k < DIM; ++k) a += pm[k] * C1[k * DIM + j];
    gv[j] = fmaxf(a, 0.f);
    __syncthreads();
    if (j < NUM_CLASSES) {
        float o = bc2[j];
        for (int k = 0; k < DIM; ++k) o += gv[k] * C2[k * NUM_CLASSES + j];
        out[g * NUM_CLASSES + j] = o;
    }
}

extern "C" void kernel_launch(void* const* d_in, const int* in_sizes, int n_in,
                              void* d_out, int out_size, void* d_ws, size_t ws_size,
                              hipStream_t stream) {
    const float* x    = (const float*)d_in[0];
    const int*   ei   = (const int*)d_in[1];
    const int*   batch= (const int*)d_in[2];
    const float* W1   = (const float*)d_in[3];
    const float* b1   = (const float*)d_in[4];
    const float* W2   = (const float*)d_in[5];
    const float* b2   = (const float*)d_in[6];
    const float* W3   = (const float*)d_in[7];
    const float* b3   = (const float*)d_in[8];
    const float* C1   = (const float*)d_in[9];
    const float* bc1  = (const float*)d_in[10];
    const float* C2   = (const float*)d_in[11];
    const float* bc2  = (const float*)d_in[12];

    const int nedges = in_sizes[1] / 2;
    const int* src = ei;
    const int* dst = ei + nedges;

    // workspace layout (4-byte units)
    float*    dinv    = (float*)d_ws;                          // NPAD
    uint_t*   Tb      = (uint_t*)(dinv + NPAD);                // N_NODES*64 (bf16 pairs)
    float*    A       = (float*)(Tb + (long long)N_NODES*64);  // 6.4M
    float*    pooled  = A + (long long)N_NODES * DIM;          // 8192
    float*    counts  = pooled + NUM_GRAPHS * DIM;             // 64
    int*      degi    = (int*)(counts + 64);                   // NPAD
    int*      rowptr  = degi + NPAD;                           // NPAD+256
    int*      bsum    = rowptr + NPAD + 256;                   // 256
    int*      rank    = bsum + 256;                            // nedges
    int*      csr_src = rank + nedges;                         // nedges
    ushort_t* Wt      = (ushort_t*)(csr_src + nedges);         // 3*16384 bf16

    const int nodeBlocks = NPAD / 256;                     // 196
    const int mmBlocks   = (N_NODES + 63) / 64;            // 782
    const int edgeBlocks = (nedges + 255) / 256;           // 3125
    const int gBlocks    = (N_NODES + 3) / 4;              // 12500
    const int poolBlocks = (N_NODES + NPB - 1) / NPB;      // 782

    k_init<<<nodeBlocks, 256, 0, stream>>>(degi, pooled, counts);
    k_prep<<<192, 256, 0, stream>>>(W1, W2, W3, Wt);
    k_count<<<edgeBlocks, 256, 0, stream>>>(dst, degi, rank, nedges);
    k_scan1<<<nodeBlocks, 256, 0, stream>>>(degi, rowptr, bsum);
    k_scan2<<<1, 256, 0, stream>>>(bsum, nodeBlocks);
    k_scan3<<<nodeBlocks, 256, 0, stream>>>(rowptr, bsum, degi, dinv);
    k_fill<<<edgeBlocks, 256, 0, stream>>>(src, dst, rank, rowptr, csr_src, nedges);

    k_matmul<false><<<mmBlocks, 256, 0, stream>>>(x, Wt,           b1, dinv, (ushort_t*)Tb, A);
    k_gather<<<gBlocks, 256, 0, stream>>>(rowptr, csr_src, dinv, Tb, A);
    k_matmul<true ><<<mmBlocks, 256, 0, stream>>>(A, Wt + 16384,   b2, dinv, (ushort_t*)Tb, A);
    k_gather<<<gBlocks, 256, 0, stream>>>(rowptr, csr_src, dinv, Tb, A);
    k_matmul<true ><<<mmBlocks, 256, 0, stream>>>(A, Wt + 32768,   b3, dinv, (ushort_t*)Tb, A);
    k_gather<<<gBlocks, 256, 0, stream>>>(rowptr, csr_src, dinv, Tb, A);

    k_pool<<<poolBlocks, 128, 0, stream>>>(A, batch, pooled, counts);
    k_cls<<<NUM_GRAPHS, 128, 0, stream>>>(pooled, counts, C1, bc1, C2, bc2,
                                          (float*)d_out);
}